// Round 5
// baseline (124.492 us; speedup 1.0000x reference)
//
#include <hip/hip_runtime.h>
#include <hip/hip_bf16.h>

#define NFFT    512
#define HOPSZ   128
#define FBINS   257
#define TFR     2048
#define NBC     32            // B*C
#define OUTLEN  262016        // (T-1)*HOP
#define SPAD    256           // n_fft/2 (center trim)

typedef __bf16 bf16x8 __attribute__((ext_vector_type(8)));
typedef float  f32x4  __attribute__((ext_vector_type(4)));

static __device__ __forceinline__ float bf2f(unsigned short u) {
    union { unsigned int i; float f; } x; x.i = (unsigned int)u << 16; return x.f;
}

__device__ __forceinline__ void gld_lds16(const void* g, void* l) {
    __builtin_amdgcn_global_load_lds(
        (const __attribute__((address_space(1))) unsigned int*)g,
        (__attribute__((address_space(3))) unsigned int*)l, 16, 0, 0);
}

#define FENCE asm volatile("" ::: "memory")
#define SYNC(N) do { asm volatile("s_waitcnt vmcnt(" #N ")" ::: "memory"); \
                     __builtin_amdgcn_s_barrier(); } while (0)

// ---------------------------------------------------------------------------
// Kernel 1: W' in MFMA A-fragment order (verified R2/R3).
//   Wf[(ks*32 + rt)*64 + lane]: 8 bf16, elem j:
//     n = rt*16 + (lane&15),  k = ks*32 + 4*(lane>>4) + (j&3) + 16*(j>>2)
// ---------------------------------------------------------------------------
__global__ __launch_bounds__(256) void k_wgen(const float* __restrict__ wnd,
                                              uint4* __restrict__ Wf) {
    const int gid  = blockIdx.x * 256 + threadIdx.x;   // < 34816
    const int lane = gid & 63;
    const int rt   = (gid >> 6) & 31;
    const int ks   = gid >> 11;
    const int n    = rt * 16 + (lane & 15);
    const int kb   = ks * 32 + ((lane >> 4) << 2);
    const float wn = wnd[n] * (1.0f / 512.0f);
    union { uint4 u; unsigned short h[8]; } o;
    #pragma unroll
    for (int j = 0; j < 8; ++j) {
        const int k = kb + (j & 3) + 16 * (j >> 2);
        float val = 0.0f;
        if (k < 2 * FBINS) {
            const int f = k >> 1;
            const bool edge = (f == 0) || (f == 256);
            const float cf = edge ? 1.0f : 2.0f;
            const int m = (f * n) & (NFFT - 1);
            const float ang = (float)m * 0.01227184630308513f; // 2*pi/512
            float s, c;
            __sincosf(ang, &s, &c);
            val = (k & 1) ? (edge ? 0.0f : -cf * wn * s) : (cf * wn * c);
        }
        __hip_bfloat16 hb = __float2bfloat16(val);
        o.h[j] = *(unsigned short*)&hb;
    }
    Wf[gid] = o.u;
}

// ---------------------------------------------------------------------------
// Kernel 2: frames(partial, k<512) = W'[:, :512] @ X.
//   2048 blocks (XCD-chunk swizzled) x 512 thr. Block: 256 rows (M-split m)
//   x 64 t (panel). 8 waves = 4 row-groups x 2 t-groups; wave = 64r x 32t,
//   acc[4][2]. K-loop = 16 full steps, no conditionals.
//   A: fragment-ordered Wf -> 3-deep LDS ring via global_load_lds; the ONLY
//      hand-managed hazard. SYNC(10) = "all but this iter's 10 VMEM done"
//      (conservative: robust to reorder/CSE; still never drains to 0).
//   B: per-wave register fragments (R2-verified layout: f0+{0,1,8,9} float2),
//      1-iter ping-pong; all waits compiler-tracked. NO ds_writes anywhere.
// ---------------------------------------------------------------------------
__global__ __launch_bounds__(512, 4) void k_mm(
    const float* __restrict__ X,
    const uint4* __restrict__ Wf,
    __hip_bfloat16* __restrict__ frames)
{
    __shared__ uint4 Ab[3][1024];   // 3 x 16 KB

    const int tid  = threadIdx.x;
    const int lane = tid & 63;
    const int w    = tid >> 6;
    const int wr   = w >> 1;            // row-group 0..3 (64 rows)
    const int wt   = w & 1;             // t-group 0..1 (32 t)

    // XCD-chunk swizzle (bijective: 2048 % 8 == 0): each XCD gets 256
    // consecutive work-ids -> shared X/Wf panels stay in its L2.
    const int bid = blockIdx.x;
    const int id  = (bid & 7) * 256 + (bid >> 3);
    const int m     = id & 1;           // M-split: rows [256m, 256m+256)
    const int panel = (id >> 1) & 31;   // 64-t panel
    const int bc    = id >> 6;          // 0..31
    const int t0b   = panel << 6;

    const float2* __restrict__ X2 = (const float2*)X + (size_t)bc * FBINS * TFR;
    const int q   = lane >> 4;
    const int rlo = lane & 15;
    const int tA  = t0b + (wt << 5) + rlo;     // t of frag ni=0 (ni=1: +16)

    f32x4  acc[4][2] = {};
    float2 xv[2][2][4];                        // [pingpong][ni][delta]

    auto issueA = [&](int ks, int buf) {       // 2x global_load_lds dwordx4
        const uint4* src = Wf + (size_t)ks * 2048 + m * 1024;
        gld_lds16(src + tid,       &Ab[buf][tid]);
        gld_lds16(src + 512 + tid, &Ab[buf][512 + tid]);
    };
    auto loadB = [&](int ks, float2 (&bx)[2][4]) {  // 8x 8B loads, f<=255
        const float2* xb = X2 + (size_t)(ks * 16 + 2 * q) * TFR;
        #pragma unroll
        for (int ni = 0; ni < 2; ++ni) {
            const float2* xt = xb + tA + ni * 16;
            bx[ni][0] = xt[0];
            bx[ni][1] = xt[TFR];
            bx[ni][2] = xt[8 * TFR];
            bx[ni][3] = xt[9 * TFR];
        }
    };
    auto compute = [&](int abuf, float2 (&bx)[2][4]) {
        uint4 b[2];
        #pragma unroll
        for (int ni = 0; ni < 2; ++ni) {
            union { unsigned short h[8]; uint4 u; } pk;
            #pragma unroll
            for (int d = 0; d < 4; ++d) {
                __hip_bfloat16 x = __float2bfloat16(bx[ni][d].x);
                __hip_bfloat16 y = __float2bfloat16(bx[ni][d].y);
                pk.h[2 * d]     = *(unsigned short*)&x;
                pk.h[2 * d + 1] = *(unsigned short*)&y;
            }
            b[ni] = pk.u;
        }
        uint4 a[4];
        const uint4* Ap = &Ab[abuf][(wr * 4) * 64 + lane];
        #pragma unroll
        for (int mi = 0; mi < 4; ++mi) a[mi] = Ap[mi * 64];
        #pragma unroll
        for (int mi = 0; mi < 4; ++mi)
            #pragma unroll
            for (int ni = 0; ni < 2; ++ni)
                acc[mi][ni] = __builtin_amdgcn_mfma_f32_16x16x32_bf16(
                    __builtin_bit_cast(bf16x8, a[mi]),
                    __builtin_bit_cast(bf16x8, b[ni]), acc[mi][ni], 0, 0, 0);
    };

    // prologue: A0,A1 + B0 in flight; SYNC(10) completes A0 (leaves A1+B0)
    issueA(0, 0);
    issueA(1, 1);
    FENCE;
    loadB(0, xv[0]);
    SYNC(10);

    #pragma unroll
    for (int i = 0; i < 14; ++i) {             // iters 0..13
        issueA(i + 2, (i + 2) % 3);            // A up to 15
        FENCE;
        loadB(i + 1, xv[(i + 1) & 1]);
        FENCE;
        compute(i % 3, xv[i & 1]);
        SYNC(10);                              // A(i+1) landed for next iter
    }
    // iter 14: no more A to issue
    loadB(15, xv[1]);
    FENCE;
    compute(14 % 3, xv[0]);
    SYNC(8);                                   // leaves only B15 -> A15 landed
    // iter 15
    compute(15 % 3, xv[1]);

    // epilogue: C/D row=(l>>4)*4+reg -> n, col=l&15 -> t (verified R1-R3)
    unsigned short* fb = (unsigned short*)frames;
    #pragma unroll
    for (int mi = 0; mi < 4; ++mi) {
        const int nbase = m * 256 + wr * 64 + mi * 16 + q * 4;
        #pragma unroll
        for (int ni = 0; ni < 2; ++ni) {
            const int t = tA + ni * 16;
            union { ushort4 u; __hip_bfloat16 hh[4]; } pk;
            pk.hh[0] = __float2bfloat16(acc[mi][ni][0]);
            pk.hh[1] = __float2bfloat16(acc[mi][ni][1]);
            pk.hh[2] = __float2bfloat16(acc[mi][ni][2]);
            pk.hh[3] = __float2bfloat16(acc[mi][ni][3]);
            *(ushort4*)(fb + (((size_t)(bc * TFR + t)) << 9) + nbase) = pk.u;
        }
    }
}

// ---------------------------------------------------------------------------
// Kernel 3: overlap-add + envelope normalize + the k=512 DC term.
//   W'[n][512] = wnd[n]*(1/512)*(-1)^n ; contribution = W'[n][512]*re(X[256,t]).
//   Parities of the 4 outputs' n alternate: +,-,+,- scaled by parity of nb.
// ---------------------------------------------------------------------------
__global__ __launch_bounds__(256) void k_ola(
    const __hip_bfloat16* __restrict__ frames,
    const float* __restrict__ wnd,
    const float* __restrict__ X,
    float* __restrict__ out)
{
    const int bc = blockIdx.y;
    const int o  = (blockIdx.x * 256 + threadIdx.x) * 4;
    if (o >= OUTLEN) return;
    const int s   = o + SPAD;
    const int tb_ = s >> 7;
    const int nb  = s & (HOPSZ - 1);
    const unsigned short* fb = (const unsigned short*)frames + (size_t)bc * TFR * NFFT;
    const float* Xre = X + (((size_t)bc * FBINS + 256) * TFR) * 2;  // re at [2t]
    const float sA = ((nb & 1) ? -1.0f : 1.0f) * (1.0f / 512.0f);
    float y0 = 0.f, y1 = 0.f, y2 = 0.f, y3 = 0.f;
    float e0 = 0.f, e1 = 0.f, e2 = 0.f, e3 = 0.f;
    #pragma unroll
    for (int r = 0; r < 4; ++r) {
        const int t = tb_ - r;
        if ((unsigned)t > (unsigned)(TFR - 1)) continue;
        const int n = nb + (r << 7);
        ushort4 v = *(const ushort4*)(fb + (size_t)t * NFFT + n);
        float4  wv = *(const float4*)(wnd + n);
        const float c = sA * Xre[2 * t];
        y0 += bf2f(v.x) + c * wv.x; e0 += wv.x * wv.x;
        y1 += bf2f(v.y) - c * wv.y; e1 += wv.y * wv.y;
        y2 += bf2f(v.z) + c * wv.z; e2 += wv.z * wv.z;
        y3 += bf2f(v.w) - c * wv.w; e3 += wv.w * wv.w;
    }
    float4 res = make_float4(y0 / e0, y1 / e1, y2 / e2, y3 / e3);
    *(float4*)(out + (size_t)bc * OUTLEN + o) = res;
}

// ---------------------------------------------------------------------------
extern "C" void kernel_launch(void* const* d_in, const int* in_sizes, int n_in,
                              void* d_out, int out_size, void* d_ws, size_t ws_size,
                              hipStream_t stream) {
    (void)in_sizes; (void)n_in; (void)out_size; (void)ws_size;
    const float* X   = (const float*)d_in[0];
    const float* wnd = (const float*)d_in[1];
    float* out = (float*)d_out;

    uint4* Wf = (uint4*)d_ws;                                            // 544 KB
    __hip_bfloat16* frames = (__hip_bfloat16*)((char*)d_ws + (1 << 20)); // 64 MB

    k_wgen<<<136, 256, 0, stream>>>(wnd, Wf);
    k_mm<<<2048, 512, 0, stream>>>(X, Wf, frames);
    k_ola<<<dim3((OUTLEN / 4 + 255) / 256, NBC), 256, 0, stream>>>(frames, wnd, X, out);
}